// Round 12
// baseline (2519.481 us; speedup 1.0000x reference)
//
#include <hip/hip_runtime.h>
#include <cstdint>

// ---------------------------------------------------------------------------
// SparseAttention — R12: GEMM register-prefetch pipelines (hide global
// latency under compute; was load->sync->write->sync->compute exposing ~500cy
// x64 iters) + attn cleanups: P stored f32 IN-PLACE in TS32 (no f16 overlay,
// no cvts, one less barrier), PV reads P via 8x ds_read_b32, QK unroll 4.
// Selection semantics identical to R3..R11 (d-ascending fp64 FMA, fp32-cast
// u32 keys via ballot search, exact-fp64 recompute tie fallback).
// ---------------------------------------------------------------------------

#define BB 2
#define NN 2048
#define CC 1024
#define HH 16
#define HD 64
#define KSP 204

__device__ __forceinline__ unsigned long long mono64(double s) {
  long long bb = __double_as_longlong(s);
  return (unsigned long long)bb ^
         ((bb < 0) ? 0xFFFFFFFFFFFFFFFFull : 0x8000000000000000ull);
}

// ---------------------------------------------------------------------------
// Kernel 1: Q,K projection in fp64. 64x64 tile, 4x4 micro, prefetched.
// ---------------------------------------------------------------------------
__global__ __launch_bounds__(256) void qk_gemm_f64(
    const float* __restrict__ x, const float* __restrict__ w,
    const float* __restrict__ bqkv, double* __restrict__ Qd,
    double* __restrict__ Kd) {
  __shared__ double As[16][64];  // [k][m]
  __shared__ double Bs[16][64];  // [k][n]
  const int tid = threadIdx.x;
  const int tx = tid & 15, ty = tid >> 4;
  const int colbase = blockIdx.x * 64, rowbase = blockIdx.y * 64;

  double acc[4][4] = {};

  const int sr = tid >> 2, sc = (tid & 3) * 4;
  const int bk = tid >> 4, bn = (tid & 15) * 4;

  const float* pa = x + (size_t)(rowbase + sr) * 1024 + sc;
  const float* pb = w + (size_t)bk * 3072 + colbase + bn;

  float4 av = *(const float4*)(pa);
  float4 bv = *(const float4*)(pb);

  for (int kt = 0; kt < 64; ++kt) {
    __syncthreads();  // previous compute done reading LDS
    As[sc + 0][sr] = (double)av.x;
    As[sc + 1][sr] = (double)av.y;
    As[sc + 2][sr] = (double)av.z;
    As[sc + 3][sr] = (double)av.w;
    Bs[bk][bn + 0] = (double)bv.x;
    Bs[bk][bn + 1] = (double)bv.y;
    Bs[bk][bn + 2] = (double)bv.z;
    Bs[bk][bn + 3] = (double)bv.w;
    __syncthreads();
    if (kt < 63) {  // prefetch next tile; latency hides under compute below
      av = *(const float4*)(pa + (kt + 1) * 16);
      bv = *(const float4*)(pb + (size_t)(kt + 1) * 16 * 3072);
    }
#pragma unroll
    for (int k = 0; k < 16; ++k) {
      double a[4], b[4];
#pragma unroll
      for (int i = 0; i < 4; ++i) a[i] = As[k][ty + 16 * i];
#pragma unroll
      for (int j = 0; j < 4; ++j) b[j] = Bs[k][tx + 16 * j];
#pragma unroll
      for (int i = 0; i < 4; ++i)
#pragma unroll
        for (int j = 0; j < 4; ++j) acc[i][j] = fma(a[i], b[j], acc[i][j]);
    }
  }

  const int region = colbase >> 10;  // 0=Q 1=K (uniform per block)
#pragma unroll
  for (int j = 0; j < 4; ++j) {
    const int col = colbase + tx + 16 * j;
    const double bias = (double)bqkv[col];
    const int h = (col & 1023) >> 6, d = col & 63;
#pragma unroll
    for (int i = 0; i < 4; ++i) {
      const int row = rowbase + ty + 16 * i;
      const int b = row >> 11, n = row & 2047;
      const size_t o = ((size_t)((b * HH + h) * HD + d)) * NN + n;
      const double v = acc[i][j] + bias;
      if (region == 0)
        Qd[o] = v * 0.125;
      else
        Kd[o] = v;
    }
  }
}

// ---------------------------------------------------------------------------
// Kernel 1b: V projection in fp32. Cols [2048,3072). Prefetched.
// ---------------------------------------------------------------------------
__global__ __launch_bounds__(256) void v_gemm_f32(
    const float* __restrict__ x, const float* __restrict__ w,
    const float* __restrict__ bqkv, float* __restrict__ Vf) {
  __shared__ float As[16][64];
  __shared__ float Bs[16][64];
  const int tid = threadIdx.x;
  const int tx = tid & 15, ty = tid >> 4;
  const int colbase = blockIdx.x * 64, rowbase = blockIdx.y * 64;

  float acc[4][4] = {};

  const int sr = tid >> 2, sc = (tid & 3) * 4;
  const int bk = tid >> 4, bn = (tid & 15) * 4;

  const float* pa = x + (size_t)(rowbase + sr) * 1024 + sc;
  const float* pb = w + (size_t)bk * 3072 + 2048 + colbase + bn;

  float4 av = *(const float4*)(pa);
  float4 bv = *(const float4*)(pb);

  for (int kt = 0; kt < 64; ++kt) {
    __syncthreads();
    As[sc + 0][sr] = av.x;
    As[sc + 1][sr] = av.y;
    As[sc + 2][sr] = av.z;
    As[sc + 3][sr] = av.w;
    Bs[bk][bn + 0] = bv.x;
    Bs[bk][bn + 1] = bv.y;
    Bs[bk][bn + 2] = bv.z;
    Bs[bk][bn + 3] = bv.w;
    __syncthreads();
    if (kt < 63) {
      av = *(const float4*)(pa + (kt + 1) * 16);
      bv = *(const float4*)(pb + (size_t)(kt + 1) * 16 * 3072);
    }
#pragma unroll
    for (int k = 0; k < 16; ++k) {
      float a[4], b[4];
#pragma unroll
      for (int i = 0; i < 4; ++i) a[i] = As[k][ty + 16 * i];
#pragma unroll
      for (int j = 0; j < 4; ++j) b[j] = Bs[k][tx + 16 * j];
#pragma unroll
      for (int i = 0; i < 4; ++i)
#pragma unroll
        for (int j = 0; j < 4; ++j) acc[i][j] = fmaf(a[i], b[j], acc[i][j]);
    }
  }

#pragma unroll
  for (int j = 0; j < 4; ++j) {
    const int col = colbase + tx + 16 * j;
    const float bias = bqkv[2048 + col];
    const int h = col >> 6, d = col & 63;
#pragma unroll
    for (int i = 0; i < 4; ++i) {
      const int row = rowbase + ty + 16 * i;
      const int b = row >> 11, n = row & 2047;
      Vf[((size_t)((b * HH + h) * HD + d)) * NN + n] = acc[i][j] + bias;
    }
  }
}

// ---------------------------------------------------------------------------
// Kernel 2: fused sparse attention. 512 thr = 8 waves, 8 q-rows/block.
// A: QK streaming (L2, no barriers). B: f32 transpose (barrier). C+D (fused,
// wave-private row): ballot select + fp64-recompute fallback, then write P
// (f32) IN PLACE over own score row + Zrow. Barrier. E: PV.
// ---------------------------------------------------------------------------
__global__ __launch_bounds__(512, 2) void attn_exact(
    const double* __restrict__ Qd, const double* __restrict__ Kd,
    const float* __restrict__ Vf, float* __restrict__ attnv) {
  __shared__ __align__(16) float TS32[8][2048];  // 64KB: scores then P (f32)
  __shared__ __align__(16) double QrowT[64][8];  // 4KB: [d][row]
  __shared__ float Zrow[8];

  const int tid = threadIdx.x;
  const int lane = tid & 63;
  const int w = tid >> 6;  // 0..7: key-slice role, row role, d-slice role

  // XCD-chunked swizzle (bijective, 8192 % 8 == 0)
  const int bid = (int)(blockIdx.x & 7) * 1024 + ((int)blockIdx.x >> 3);
  const int bh = bid >> 8;
  const int n0 = (bid & 255) * 8;

  const double* Kbh = Kd + (size_t)bh * HD * NN;

  {  // stage Q: 512 values, one per thread
    const int d = tid >> 3, r = tid & 7;
    QrowT[d][r] = Qd[((size_t)bh * HD + d) * NN + n0 + r];
  }
  __syncthreads();

  // ---- Phase A: QK^T, stream K from L2, no barriers.
  //      acc[r][j]: key = 256w + 2*lane + (j&1) + 128*(j>>1); d-ascending. ----
  double acc[8][4];
#pragma unroll
  for (int r = 0; r < 8; ++r)
#pragma unroll
    for (int j = 0; j < 4; ++j) acc[r][j] = 0.0;

  {
    const double* kp = Kbh + w * 256 + 2 * lane;
#pragma unroll 4
    for (int d = 0; d < 64; ++d) {
      const double* kr = kp + (size_t)d * NN;
      const double2 kv0 = *(const double2*)(kr);
      const double2 kv1 = *(const double2*)(kr + 128);
      double q[8];
#pragma unroll
      for (int rp = 0; rp < 4; ++rp)
        *(double2*)&q[rp * 2] = *(const double2*)&QrowT[d][rp * 2];
#pragma unroll
      for (int r = 0; r < 8; ++r) {
        acc[r][0] = fma(q[r], kv0.x, acc[r][0]);
        acc[r][1] = fma(q[r], kv0.y, acc[r][1]);
        acc[r][2] = fma(q[r], kv1.x, acc[r][2]);
        acc[r][3] = fma(q[r], kv1.y, acc[r][3]);
      }
    }
  }

  // ---- Phase B: f32 transpose of ALL 8 rows (float2 writes) ----
#pragma unroll
  for (int r = 0; r < 8; ++r) {
    float2 t0, t1;
    t0.x = (float)acc[r][0];
    t0.y = (float)acc[r][1];
    t1.x = (float)acc[r][2];
    t1.y = (float)acc[r][3];
    *(float2*)&TS32[r][w * 256 + 2 * lane] = t0;
    *(float2*)&TS32[r][w * 256 + 128 + 2 * lane] = t1;
  }
  __syncthreads();

  // ---- Phase C+D (fused; wave-private row): select, then write P in place ----
  {
    unsigned ka[32];
    unsigned selmask = 0;
    float mxf;
    unsigned kmax = 0;
#pragma unroll
    for (int i = 0; i < 32; ++i) {
      const int ib = __float_as_int(TS32[w][lane + 64 * i]);
      ka[i] = (unsigned)ib ^ ((ib < 0) ? 0xFFFFFFFFu : 0x80000000u);
      kmax = (ka[i] > kmax) ? ka[i] : kmax;
    }
#pragma unroll
    for (int m = 1; m < 64; m <<= 1) {
      const unsigned o = __shfl_xor(kmax, m, 64);
      kmax = (o > kmax) ? o : kmax;
    }
    mxf = __int_as_float(
        (int)((kmax & 0x80000000u) ? (kmax ^ 0x80000000u) : ~kmax));

    unsigned T32 = 0;
#pragma unroll 1
    for (int bit = 31; bit >= 0; --bit) {
      const unsigned cand = T32 | (1u << bit);
      int c = 0;
#pragma unroll
      for (int i = 0; i < 32; ++i) c += __popcll(__ballot(ka[i] >= cand));
      if (c >= KSP) T32 = cand;
    }

    int cgt = 0, ceq = 0;
#pragma unroll
    for (int i = 0; i < 32; ++i) {
      cgt += __popcll(__ballot(ka[i] > T32));
      ceq += __popcll(__ballot(ka[i] == T32));
    }

    if (cgt + ceq == KSP) {  // common: fp32-level selection exact
#pragma unroll
      for (int i = 0; i < 32; ++i)
        selmask |= (ka[i] >= T32) ? (1u << i) : 0u;
    } else {
      // rare: recompute this row's fp64 scores (same d-ascending fma chain
      // as phase A => bit-identical), then 64-bit search among ties.
      double sv[32];
#pragma unroll
      for (int i = 0; i < 32; ++i) sv[i] = 0.0;
#pragma unroll 1
      for (int d = 0; d < 64; ++d) {
        const double qd = QrowT[d][w];
        const double* kr = Kbh + (size_t)d * NN + lane;
#pragma unroll
        for (int i = 0; i < 32; ++i) sv[i] = fma(qd, kr[64 * i], sv[i]);
      }
      unsigned long long T = 0ull;
#pragma unroll 1
      for (int bit = 63; bit >= 0; --bit) {
        const unsigned long long cand = T | (1ull << bit);
        int c = 0;
#pragma unroll
        for (int i = 0; i < 32; ++i)
          c += __popcll(__ballot(ka[i] == T32 && mono64(sv[i]) >= cand));
        if (cgt + c >= KSP) T = cand;
      }
#pragma unroll
      for (int i = 0; i < 32; ++i)
        selmask |= ((ka[i] > T32) || (ka[i] == T32 && mono64(sv[i]) >= T))
                       ? (1u << i)
                       : 0u;
    }

    // Phase D (no barrier needed — own row only): P (f32) in place + Z
    float z = 0.f;
#pragma unroll
    for (int i = 0; i < 32; ++i) {
      const float f = __int_as_float(
          (int)((ka[i] & 0x80000000u) ? (ka[i] ^ 0x80000000u) : ~ka[i]));
      const float p = ((selmask >> i) & 1u) ? __expf(f - mxf) : 0.0f;
      TS32[w][lane + 64 * i] = p;
      z += p;
    }
#pragma unroll
    for (int m = 1; m < 64; m <<= 1) z += __shfl_xor(z, m, 64);
    if (lane == 0) Zrow[w] = z;
  }
  __syncthreads();  // P + Zrow visible to all waves

  // ---- Phase E: PV, wave w owns d in [8w,8w+8), two halves of 4 ----
  const int b2 = bh >> 4, h2 = bh & 15;
#define PV_HALF(H)                                                            \
  {                                                                           \
    float s[4][8];                                                            \
    _Pragma("unroll") for (int d4 = 0; d4 < 4; ++d4)                          \
        _Pragma("unroll") for (int r = 0; r < 8; ++r) s[d4][r] = 0.f;         \
    const float* vb = Vf + ((size_t)bh * HD + 8 * w + (H)*4) * NN;            \
    _Pragma("unroll 2") for (int i = 0; i < 32; ++i) {                        \
      const int k = lane + 64 * i;                                            \
      float pf[8];                                                            \
      _Pragma("unroll") for (int r = 0; r < 8; ++r) pf[r] = TS32[r][k];       \
      float vv[4];                                                            \
      _Pragma("unroll") for (int d4 = 0; d4 < 4; ++d4) vv[d4] =               \
          vb[(size_t)d4 * NN + k];                                            \
      _Pragma("unroll") for (int d4 = 0; d4 < 4; ++d4)                        \
          _Pragma("unroll") for (int r = 0; r < 8; ++r) s[d4][r] =            \
              fmaf(pf[r], vv[d4], s[d4][r]);                                  \
    }                                                                         \
    _Pragma("unroll") for (int d4 = 0; d4 < 4; ++d4)                          \
        _Pragma("unroll") for (int r = 0; r < 8; ++r) {                       \
      float v = s[d4][r];                                                     \
      _Pragma("unroll") for (int m = 1; m < 64; m <<= 1) v +=                 \
          __shfl_xor(v, m, 64);                                               \
      if (lane == 0)                                                          \
        attnv[((size_t)(b2 * NN + n0 + r)) * CC + h2 * HD + 8 * w + (H)*4 +   \
              d4] = v / Zrow[r];                                              \
    }                                                                         \
  }

  PV_HALF(0)
  PV_HALF(1)
}

// ---------------------------------------------------------------------------
// Kernel 3: out = attnv @ w_out + b_out, fp32, 64x64 tile, prefetched.
// ---------------------------------------------------------------------------
__global__ __launch_bounds__(256) void out_gemm_f32(
    const float* __restrict__ A, const float* __restrict__ W,
    const float* __restrict__ bout, float* __restrict__ out) {
  __shared__ float As[16][64];
  __shared__ float Bs[16][64];
  const int tid = threadIdx.x;
  const int tx = tid & 15, ty = tid >> 4;
  const int colbase = blockIdx.x * 64, rowbase = blockIdx.y * 64;

  float acc[4][4] = {};

  const int sr = tid >> 2, sc = (tid & 3) * 4;
  const int bk = tid >> 4, bn = (tid & 15) * 4;

  const float* pa = A + (size_t)(rowbase + sr) * 1024 + sc;
  const float* pb = W + (size_t)bk * 1024 + colbase + bn;

  float4 av = *(const float4*)(pa);
  float4 bv = *(const float4*)(pb);

  for (int kt = 0; kt < 64; ++kt) {
    __syncthreads();
    As[sc + 0][sr] = av.x;
    As[sc + 1][sr] = av.y;
    As[sc + 2][sr] = av.z;
    As[sc + 3][sr] = av.w;
    Bs[bk][bn + 0] = bv.x;
    Bs[bk][bn + 1] = bv.y;
    Bs[bk][bn + 2] = bv.z;
    Bs[bk][bn + 3] = bv.w;
    __syncthreads();
    if (kt < 63) {
      av = *(const float4*)(pa + (kt + 1) * 16);
      bv = *(const float4*)(pb + (size_t)(kt + 1) * 16 * 1024);
    }
#pragma unroll
    for (int k = 0; k < 16; ++k) {
      float a[4], b[4];
#pragma unroll
      for (int i = 0; i < 4; ++i) a[i] = As[k][ty + 16 * i];
#pragma unroll
      for (int j = 0; j < 4; ++j) b[j] = Bs[k][tx + 16 * j];
#pragma unroll
      for (int i = 0; i < 4; ++i)
#pragma unroll
        for (int j = 0; j < 4; ++j) acc[i][j] = fmaf(a[i], b[j], acc[i][j]);
    }
  }

#pragma unroll
  for (int j = 0; j < 4; ++j) {
    const int col = colbase + tx + 16 * j;
    const float bias = bout[col];
#pragma unroll
    for (int i = 0; i < 4; ++i) {
      const int row = rowbase + ty + 16 * i;
      out[(size_t)row * CC + col] = acc[i][j] + bias;
    }
  }
}

// ---------------------------------------------------------------------------
extern "C" void kernel_launch(void* const* d_in, const int* in_sizes, int n_in,
                              void* d_out, int out_size, void* d_ws,
                              size_t ws_size, hipStream_t stream) {
  const float* x     = (const float*)d_in[0];
  const float* w_qkv = (const float*)d_in[1];
  const float* b_qkv = (const float*)d_in[2];
  const float* w_out = (const float*)d_in[3];
  const float* b_out = (const float*)d_in[4];
  float* out = (float*)d_out;

  char* ws = (char*)d_ws;
  const size_t SZ_QD = (size_t)BB * HH * HD * NN * 8;  // 33.55 MB
  const size_t SZ_VF = (size_t)BB * HH * HD * NN * 4;  // 16.78 MB
  const size_t SZ_AT = (size_t)4096 * 1024 * 4;        // 16.78 MB

  size_t off = 0;
  double* Qd    = (double*)(ws + off); off += SZ_QD;
  double* Kd    = (double*)(ws + off); off += SZ_QD;
  float*  Vf    = (float*)(ws + off);  off += SZ_VF;
  float*  attnv = (float*)(ws + off);  off += SZ_AT;

  {
    dim3 g(2048 / 64, 4096 / 64);
    qk_gemm_f64<<<g, 256, 0, stream>>>(x, w_qkv, b_qkv, Qd, Kd);
  }
  {
    dim3 g(1024 / 64, 4096 / 64);
    v_gemm_f32<<<g, 256, 0, stream>>>(x, w_qkv, b_qkv, Vf);
  }
  attn_exact<<<BB * HH * (NN / 8), 512, 0, stream>>>(Qd, Kd, Vf, attnv);
  {
    dim3 g(1024 / 64, 4096 / 64);
    out_gemm_f32<<<g, 256, 0, stream>>>(attnv, w_out, b_out, out);
  }
}

// Round 13
// 1923.425 us; speedup vs baseline: 1.3099x; 1.3099x over previous
//
#include <hip/hip_runtime.h>
#include <cstdint>

// ---------------------------------------------------------------------------
// SparseAttention — R13: consolidation. attn = R11 kernel VERBATIM (VGPR 64
// => 2 blocks/CU => 1223us; R12's tweaks crossed the 64-VGPR HW allocation
// step and halved occupancy). GEMMs = R12 register-prefetch pipelines (kept;
// total-minus-attn 717->673us). No other edits.
// Selection semantics identical to R3..R12 (absmax must stay 2.563477e-3).
// ---------------------------------------------------------------------------

#define BB 2
#define NN 2048
#define CC 1024
#define HH 16
#define HD 64
#define KSP 204

typedef _Float16 f16x8v __attribute__((ext_vector_type(8)));

__device__ __forceinline__ unsigned long long mono64(double s) {
  long long bb = __double_as_longlong(s);
  return (unsigned long long)bb ^
         ((bb < 0) ? 0xFFFFFFFFFFFFFFFFull : 0x8000000000000000ull);
}

// ---------------------------------------------------------------------------
// Kernel 1: Q,K projection in fp64. 64x64 tile, 4x4 micro, prefetched. (R12)
// ---------------------------------------------------------------------------
__global__ __launch_bounds__(256) void qk_gemm_f64(
    const float* __restrict__ x, const float* __restrict__ w,
    const float* __restrict__ bqkv, double* __restrict__ Qd,
    double* __restrict__ Kd) {
  __shared__ double As[16][64];  // [k][m]
  __shared__ double Bs[16][64];  // [k][n]
  const int tid = threadIdx.x;
  const int tx = tid & 15, ty = tid >> 4;
  const int colbase = blockIdx.x * 64, rowbase = blockIdx.y * 64;

  double acc[4][4] = {};

  const int sr = tid >> 2, sc = (tid & 3) * 4;
  const int bk = tid >> 4, bn = (tid & 15) * 4;

  const float* pa = x + (size_t)(rowbase + sr) * 1024 + sc;
  const float* pb = w + (size_t)bk * 3072 + colbase + bn;

  float4 av = *(const float4*)(pa);
  float4 bv = *(const float4*)(pb);

  for (int kt = 0; kt < 64; ++kt) {
    __syncthreads();  // previous compute done reading LDS
    As[sc + 0][sr] = (double)av.x;
    As[sc + 1][sr] = (double)av.y;
    As[sc + 2][sr] = (double)av.z;
    As[sc + 3][sr] = (double)av.w;
    Bs[bk][bn + 0] = (double)bv.x;
    Bs[bk][bn + 1] = (double)bv.y;
    Bs[bk][bn + 2] = (double)bv.z;
    Bs[bk][bn + 3] = (double)bv.w;
    __syncthreads();
    if (kt < 63) {  // prefetch next tile; latency hides under compute below
      av = *(const float4*)(pa + (kt + 1) * 16);
      bv = *(const float4*)(pb + (size_t)(kt + 1) * 16 * 3072);
    }
#pragma unroll
    for (int k = 0; k < 16; ++k) {
      double a[4], b[4];
#pragma unroll
      for (int i = 0; i < 4; ++i) a[i] = As[k][ty + 16 * i];
#pragma unroll
      for (int j = 0; j < 4; ++j) b[j] = Bs[k][tx + 16 * j];
#pragma unroll
      for (int i = 0; i < 4; ++i)
#pragma unroll
        for (int j = 0; j < 4; ++j) acc[i][j] = fma(a[i], b[j], acc[i][j]);
    }
  }

  const int region = colbase >> 10;  // 0=Q 1=K (uniform per block)
#pragma unroll
  for (int j = 0; j < 4; ++j) {
    const int col = colbase + tx + 16 * j;
    const double bias = (double)bqkv[col];
    const int h = (col & 1023) >> 6, d = col & 63;
#pragma unroll
    for (int i = 0; i < 4; ++i) {
      const int row = rowbase + ty + 16 * i;
      const int b = row >> 11, n = row & 2047;
      const size_t o = ((size_t)((b * HH + h) * HD + d)) * NN + n;
      const double v = acc[i][j] + bias;
      if (region == 0)
        Qd[o] = v * 0.125;
      else
        Kd[o] = v;
    }
  }
}

// ---------------------------------------------------------------------------
// Kernel 1b: V projection in fp32. Cols [2048,3072). Prefetched. (R12)
// ---------------------------------------------------------------------------
__global__ __launch_bounds__(256) void v_gemm_f32(
    const float* __restrict__ x, const float* __restrict__ w,
    const float* __restrict__ bqkv, float* __restrict__ Vf) {
  __shared__ float As[16][64];
  __shared__ float Bs[16][64];
  const int tid = threadIdx.x;
  const int tx = tid & 15, ty = tid >> 4;
  const int colbase = blockIdx.x * 64, rowbase = blockIdx.y * 64;

  float acc[4][4] = {};

  const int sr = tid >> 2, sc = (tid & 3) * 4;
  const int bk = tid >> 4, bn = (tid & 15) * 4;

  const float* pa = x + (size_t)(rowbase + sr) * 1024 + sc;
  const float* pb = w + (size_t)bk * 3072 + 2048 + colbase + bn;

  float4 av = *(const float4*)(pa);
  float4 bv = *(const float4*)(pb);

  for (int kt = 0; kt < 64; ++kt) {
    __syncthreads();
    As[sc + 0][sr] = av.x;
    As[sc + 1][sr] = av.y;
    As[sc + 2][sr] = av.z;
    As[sc + 3][sr] = av.w;
    Bs[bk][bn + 0] = bv.x;
    Bs[bk][bn + 1] = bv.y;
    Bs[bk][bn + 2] = bv.z;
    Bs[bk][bn + 3] = bv.w;
    __syncthreads();
    if (kt < 63) {
      av = *(const float4*)(pa + (kt + 1) * 16);
      bv = *(const float4*)(pb + (size_t)(kt + 1) * 16 * 3072);
    }
#pragma unroll
    for (int k = 0; k < 16; ++k) {
      float a[4], b[4];
#pragma unroll
      for (int i = 0; i < 4; ++i) a[i] = As[k][ty + 16 * i];
#pragma unroll
      for (int j = 0; j < 4; ++j) b[j] = Bs[k][tx + 16 * j];
#pragma unroll
      for (int i = 0; i < 4; ++i)
#pragma unroll
        for (int j = 0; j < 4; ++j) acc[i][j] = fmaf(a[i], b[j], acc[i][j]);
    }
  }

#pragma unroll
  for (int j = 0; j < 4; ++j) {
    const int col = colbase + tx + 16 * j;
    const float bias = bqkv[2048 + col];
    const int h = col >> 6, d = col & 63;
#pragma unroll
    for (int i = 0; i < 4; ++i) {
      const int row = rowbase + ty + 16 * i;
      const int b = row >> 11, n = row & 2047;
      Vf[((size_t)((b * HH + h) * HD + d)) * NN + n] = acc[i][j] + bias;
    }
  }
}

// ---------------------------------------------------------------------------
// Kernel 2: fused sparse attention — R11 VERBATIM. 512 thr = 8 waves.
// Wave w: QK on keys [256w,256w+256) -> f32 transpose -> select own row
// (ballot binary search; fp64 recompute fallback) -> softmax write (Pp f16
// overlays TS) -> PV on d in [8w,8w+8).
// ---------------------------------------------------------------------------
__global__ __launch_bounds__(512, 2) void attn_exact(
    const double* __restrict__ Qd, const double* __restrict__ Kd,
    const float* __restrict__ Vf, float* __restrict__ attnv) {
  __shared__ __align__(16) float TS32[8][2048];  // 64KB; Pp overlays after B
  __shared__ __align__(16) double QrowT[64][8];  // 4KB: [d][row]
  __shared__ float Zrow[8];

  _Float16* Pp = (_Float16*)&TS32[0][0];  // [key][8 rows] f16, 32KB

  const int tid = threadIdx.x;
  const int lane = tid & 63;
  const int w = tid >> 6;  // 0..7: key-slice role, row role, d-slice role

  // XCD-chunked swizzle (bijective, 8192 % 8 == 0)
  const int bid = (int)(blockIdx.x & 7) * 1024 + ((int)blockIdx.x >> 3);
  const int bh = bid >> 8;
  const int n0 = (bid & 255) * 8;

  const double* Kbh = Kd + (size_t)bh * HD * NN;

  {  // stage Q: 512 values, one per thread
    const int d = tid >> 3, r = tid & 7;
    QrowT[d][r] = Qd[((size_t)bh * HD + d) * NN + n0 + r];
  }
  __syncthreads();

  // ---- Phase A: QK^T, stream K from L2, no barriers.
  //      acc[r][j]: key = 256w + 2*lane + (j&1) + 128*(j>>1); d-ascending. ----
  double acc[8][4];
#pragma unroll
  for (int r = 0; r < 8; ++r)
#pragma unroll
    for (int j = 0; j < 4; ++j) acc[r][j] = 0.0;

  {
    const double* kp = Kbh + w * 256 + 2 * lane;
#pragma unroll 2
    for (int d = 0; d < 64; ++d) {
      const double* kr = kp + (size_t)d * NN;
      const double2 kv0 = *(const double2*)(kr);
      const double2 kv1 = *(const double2*)(kr + 128);
      double q[8];
#pragma unroll
      for (int rp = 0; rp < 4; ++rp)
        *(double2*)&q[rp * 2] = *(const double2*)&QrowT[d][rp * 2];
#pragma unroll
      for (int r = 0; r < 8; ++r) {
        acc[r][0] = fma(q[r], kv0.x, acc[r][0]);
        acc[r][1] = fma(q[r], kv0.y, acc[r][1]);
        acc[r][2] = fma(q[r], kv1.x, acc[r][2]);
        acc[r][3] = fma(q[r], kv1.y, acc[r][3]);
      }
    }
  }

  // ---- Phase B: f32 transpose of ALL 8 rows (float2 writes) ----
#pragma unroll
  for (int r = 0; r < 8; ++r) {
    float2 t0, t1;
    t0.x = (float)acc[r][0];
    t0.y = (float)acc[r][1];
    t1.x = (float)acc[r][2];
    t1.y = (float)acc[r][3];
    *(float2*)&TS32[r][w * 256 + 2 * lane] = t0;
    *(float2*)&TS32[r][w * 256 + 128 + 2 * lane] = t1;
  }
  __syncthreads();

  // ---- Phase C: every wave selects its own row (ballot binary search) ----
  unsigned ka[32];
  unsigned selmask = 0;
  float mxf;
  {
    unsigned kmax = 0;
#pragma unroll
    for (int i = 0; i < 32; ++i) {
      const int ib = __float_as_int(TS32[w][lane + 64 * i]);
      ka[i] = (unsigned)ib ^ ((ib < 0) ? 0xFFFFFFFFu : 0x80000000u);
      kmax = (ka[i] > kmax) ? ka[i] : kmax;
    }
#pragma unroll
    for (int m = 1; m < 64; m <<= 1) {
      const unsigned o = __shfl_xor(kmax, m, 64);
      kmax = (o > kmax) ? o : kmax;
    }
    mxf = __int_as_float(
        (int)((kmax & 0x80000000u) ? (kmax ^ 0x80000000u) : ~kmax));

    unsigned T32 = 0;
#pragma unroll 1
    for (int bit = 31; bit >= 0; --bit) {
      const unsigned cand = T32 | (1u << bit);
      int c = 0;
#pragma unroll
      for (int i = 0; i < 32; ++i) c += __popcll(__ballot(ka[i] >= cand));
      if (c >= KSP) T32 = cand;
    }

    int cgt = 0, ceq = 0;
#pragma unroll
    for (int i = 0; i < 32; ++i) {
      cgt += __popcll(__ballot(ka[i] > T32));
      ceq += __popcll(__ballot(ka[i] == T32));
    }

    if (cgt + ceq == KSP) {  // common: fp32-level selection exact
#pragma unroll
      for (int i = 0; i < 32; ++i)
        selmask |= (ka[i] >= T32) ? (1u << i) : 0u;
    } else {
      // rare: recompute this row's fp64 scores (same d-ascending fma chain
      // as phase A => bit-identical), then 64-bit search among ties.
      double sv[32];
#pragma unroll
      for (int i = 0; i < 32; ++i) sv[i] = 0.0;
#pragma unroll 1
      for (int d = 0; d < 64; ++d) {
        const double qd = QrowT[d][w];
        const double* kr = Kbh + (size_t)d * NN + lane;
#pragma unroll
        for (int i = 0; i < 32; ++i) sv[i] = fma(qd, kr[64 * i], sv[i]);
      }
      unsigned long long T = 0ull;
#pragma unroll 1
      for (int bit = 63; bit >= 0; --bit) {
        const unsigned long long cand = T | (1ull << bit);
        int c = 0;
#pragma unroll
        for (int i = 0; i < 32; ++i)
          c += __popcll(__ballot(ka[i] == T32 && mono64(sv[i]) >= cand));
        if (cgt + c >= KSP) T = cand;
      }
#pragma unroll
      for (int i = 0; i < 32; ++i)
        selmask |= ((ka[i] > T32) || (ka[i] == T32 && mono64(sv[i]) >= T))
                       ? (1u << i)
                       : 0u;
    }
  }
  __syncthreads();  // all TS reads done before Pp overlay

  // ---- Phase D: softmax numerators from ka bits; write Pp (f16) + Z ----
  {
    float z = 0.f;
#pragma unroll
    for (int i = 0; i < 32; ++i) {
      const float f = __int_as_float(
          (int)((ka[i] & 0x80000000u) ? (ka[i] ^ 0x80000000u) : ~ka[i]));
      const float p = ((selmask >> i) & 1u) ? __expf(f - mxf) : 0.0f;
      Pp[(lane + 64 * i) * 8 + w] = (_Float16)p;
      z += p;
    }
#pragma unroll
    for (int m = 1; m < 64; m <<= 1) z += __shfl_xor(z, m, 64);
    if (lane == 0) Zrow[w] = z;
  }
  __syncthreads();

  // ---- Phase E: PV, wave w owns d in [8w,8w+8), two halves of 4 ----
  const int b2 = bh >> 4, h2 = bh & 15;
#define PV_HALF(H)                                                            \
  {                                                                           \
    float s[4][8];                                                            \
    _Pragma("unroll") for (int d4 = 0; d4 < 4; ++d4)                          \
        _Pragma("unroll") for (int r = 0; r < 8; ++r) s[d4][r] = 0.f;         \
    const float* vb = Vf + ((size_t)bh * HD + 8 * w + (H)*4) * NN;            \
    _Pragma("unroll 2") for (int i = 0; i < 32; ++i) {                        \
      const int k = lane + 64 * i;                                            \
      const f16x8v pk = *(const f16x8v*)&Pp[k * 8];                           \
      float pf[8];                                                            \
      _Pragma("unroll") for (int r = 0; r < 8; ++r) pf[r] = (float)pk[r];     \
      float vv[4];                                                            \
      _Pragma("unroll") for (int d4 = 0; d4 < 4; ++d4) vv[d4] =               \
          vb[(size_t)d4 * NN + k];                                            \
      _Pragma("unroll") for (int d4 = 0; d4 < 4; ++d4)                        \
          _Pragma("unroll") for (int r = 0; r < 8; ++r) s[d4][r] =            \
              fmaf(pf[r], vv[d4], s[d4][r]);                                  \
    }                                                                         \
    _Pragma("unroll") for (int d4 = 0; d4 < 4; ++d4)                          \
        _Pragma("unroll") for (int r = 0; r < 8; ++r) {                       \
      float v = s[d4][r];                                                     \
      _Pragma("unroll") for (int m = 1; m < 64; m <<= 1) v +=                 \
          __shfl_xor(v, m, 64);                                               \
      if (lane == 0)                                                          \
        attnv[((size_t)(b2 * NN + n0 + r)) * CC + h2 * HD + 8 * w + (H)*4 +   \
              d4] = v / Zrow[r];                                              \
    }                                                                         \
  }

  PV_HALF(0)
  PV_HALF(1)
}

// ---------------------------------------------------------------------------
// Kernel 3: out = attnv @ w_out + b_out, fp32, 64x64 tile, prefetched. (R12)
// ---------------------------------------------------------------------------
__global__ __launch_bounds__(256) void out_gemm_f32(
    const float* __restrict__ A, const float* __restrict__ W,
    const float* __restrict__ bout, float* __restrict__ out) {
  __shared__ float As[16][64];
  __shared__ float Bs[16][64];
  const int tid = threadIdx.x;
  const int tx = tid & 15, ty = tid >> 4;
  const int colbase = blockIdx.x * 64, rowbase = blockIdx.y * 64;

  float acc[4][4] = {};

  const int sr = tid >> 2, sc = (tid & 3) * 4;
  const int bk = tid >> 4, bn = (tid & 15) * 4;

  const float* pa = A + (size_t)(rowbase + sr) * 1024 + sc;
  const float* pb = W + (size_t)bk * 1024 + colbase + bn;

  float4 av = *(const float4*)(pa);
  float4 bv = *(const float4*)(pb);

  for (int kt = 0; kt < 64; ++kt) {
    __syncthreads();
    As[sc + 0][sr] = av.x;
    As[sc + 1][sr] = av.y;
    As[sc + 2][sr] = av.z;
    As[sc + 3][sr] = av.w;
    Bs[bk][bn + 0] = bv.x;
    Bs[bk][bn + 1] = bv.y;
    Bs[bk][bn + 2] = bv.z;
    Bs[bk][bn + 3] = bv.w;
    __syncthreads();
    if (kt < 63) {
      av = *(const float4*)(pa + (kt + 1) * 16);
      bv = *(const float4*)(pb + (size_t)(kt + 1) * 16 * 1024);
    }
#pragma unroll
    for (int k = 0; k < 16; ++k) {
      float a[4], b[4];
#pragma unroll
      for (int i = 0; i < 4; ++i) a[i] = As[k][ty + 16 * i];
#pragma unroll
      for (int j = 0; j < 4; ++j) b[j] = Bs[k][tx + 16 * j];
#pragma unroll
      for (int i = 0; i < 4; ++i)
#pragma unroll
        for (int j = 0; j < 4; ++j) acc[i][j] = fmaf(a[i], b[j], acc[i][j]);
    }
  }

#pragma unroll
  for (int j = 0; j < 4; ++j) {
    const int col = colbase + tx + 16 * j;
    const float bias = bout[col];
#pragma unroll
    for (int i = 0; i < 4; ++i) {
      const int row = rowbase + ty + 16 * i;
      out[(size_t)row * CC + col] = acc[i][j] + bias;
    }
  }
}

// ---------------------------------------------------------------------------
extern "C" void kernel_launch(void* const* d_in, const int* in_sizes, int n_in,
                              void* d_out, int out_size, void* d_ws,
                              size_t ws_size, hipStream_t stream) {
  const float* x     = (const float*)d_in[0];
  const float* w_qkv = (const float*)d_in[1];
  const float* b_qkv = (const float*)d_in[2];
  const float* w_out = (const float*)d_in[3];
  const float* b_out = (const float*)d_in[4];
  float* out = (float*)d_out;

  char* ws = (char*)d_ws;
  const size_t SZ_QD = (size_t)BB * HH * HD * NN * 8;  // 33.55 MB
  const size_t SZ_VF = (size_t)BB * HH * HD * NN * 4;  // 16.78 MB
  const size_t SZ_AT = (size_t)4096 * 1024 * 4;        // 16.78 MB

  size_t off = 0;
  double* Qd    = (double*)(ws + off); off += SZ_QD;
  double* Kd    = (double*)(ws + off); off += SZ_QD;
  float*  Vf    = (float*)(ws + off);  off += SZ_VF;
  float*  attnv = (float*)(ws + off);  off += SZ_AT;

  {
    dim3 g(2048 / 64, 4096 / 64);
    qk_gemm_f64<<<g, 256, 0, stream>>>(x, w_qkv, b_qkv, Qd, Kd);
  }
  {
    dim3 g(1024 / 64, 4096 / 64);
    v_gemm_f32<<<g, 256, 0, stream>>>(x, w_qkv, b_qkv, Vf);
  }
  attn_exact<<<BB * HH * (NN / 8), 512, 0, stream>>>(Qd, Kd, Vf, attnv);
  {
    dim3 g(1024 / 64, 4096 / 64);
    out_gemm_f32<<<g, 256, 0, stream>>>(attnv, w_out, b_out, out);
  }
}